// Round 1
// baseline (601.463 us; speedup 1.0000x reference)
//
#include <hip/hip_runtime.h>

#define H 512
#define W 512
#define XH 513
#define TILE 16
#define FT (TILE + 4)      // 20: feat tile with 2-halo each side
#define FS (FT + 1)        // 21: LDS stride

// ws layout (floats):
// [0, 1200)    : P[4][25][12] = {w0..w8, Bfull, enc_b, pad} per (q, j)
// [1200, 2100) : Bc[100][9]   (per-tap bias, for border correction)

__global__ __launch_bounds__(1024)
void prep_kernel(const float* __restrict__ comp_w, const float* __restrict__ comp_b,
                 const float* __restrict__ enc_w, const float* __restrict__ enc_b,
                 float* __restrict__ ws) {
  int t = threadIdx.x;
  float* P  = ws;
  float* Bc = ws + 1200;
  if (t < 900) {
    int o = t / 9, tap = t % 9;
    float sw = 0.f, sb = 0.f;
    for (int c = 0; c < 64; ++c) {
      float e = enc_w[(o * 64 + c) * 9 + tap];
      sw += e * comp_w[c];
      sb += e * comp_b[c];
    }
    int q = o & 3, j = o >> 2;
    P[(q * 25 + j) * 12 + tap] = sw;
    Bc[o * 9 + tap] = sb;
  }
  __syncthreads();
  if (t < 100) {
    int o = t;
    float s = enc_b[o];
    for (int i = 0; i < 9; ++i) s += Bc[o * 9 + i];
    int q = o & 3, j = o >> 2;
    P[(q * 25 + j) * 12 + 9]  = s;         // Bfull (interior bias)
    P[(q * 25 + j) * 12 + 10] = enc_b[o];  // raw enc bias (border path)
    P[(q * 25 + j) * 12 + 11] = 0.f;
  }
}

__global__ __launch_bounds__(256)
void carafe_kernel(const float* __restrict__ x,
                   const float* __restrict__ conv_w, const float* __restrict__ conv_b,
                   const float* __restrict__ ws,
                   float* __restrict__ out) {
  __shared__ __align__(16) float sP[1200];
  __shared__ float sBc[900];
  __shared__ float sF[FT][FS];

  int tid = threadIdx.x;
  for (int i = tid; i < 1200; i += 256) sP[i] = ws[i];
  for (int i = tid; i < 900;  i += 256) sBc[i] = ws[1200 + i];

  int n  = blockIdx.z;
  int h0 = blockIdx.y * TILE;
  int w0 = blockIdx.x * TILE;

  float w00 = conv_w[0], w01 = conv_w[1], w10 = conv_w[2], w11 = conv_w[3];
  float cb  = conv_b[0];
  const float* xn = x + (size_t)n * XH * XH;

  // feat tile with 2-halo: feat(h,w) = cb + 2x2 conv of x, zero outside [0,512)^2
  for (int i = tid; i < FT * FT; i += 256) {
    int r = i / FT, c = i - r * FT;
    int h = h0 - 2 + r, w = w0 - 2 + c;
    float v = 0.f;
    if (h >= 0 && h < H && w >= 0 && w < W) {
      const float* p = xn + (size_t)h * XH + w;
      v = cb + w00 * p[0] + w01 * p[1] + w10 * p[XH] + w11 * p[XH + 1];
    }
    sF[r][c] = v;
  }
  __syncthreads();

  int ty = tid >> 4, tx = tid & 15;
  int h = h0 + ty, w = w0 + tx;

  float f[5][5];
  #pragma unroll
  for (int i = 0; i < 5; ++i)
    #pragma unroll
    for (int j = 0; j < 5; ++j)
      f[i][j] = sF[ty + i][tx + j];

  bool interior = (h >= 1) & (h < H - 1) & (w >= 1) & (w < W - 1);
  float vm[9];
  #pragma unroll
  for (int t9 = 0; t9 < 9; ++t9) {
    int dh = t9 / 3 - 1, dw = t9 % 3 - 1;
    vm[t9] = (h + dh >= 0 && h + dh < H && w + dw >= 0 && w + dw < W) ? 1.f : 0.f;
  }

  float r[4];
  #pragma unroll 1
  for (int q = 0; q < 4; ++q) {
    float lg[25];
    float mx = -1e30f;
    #pragma unroll
    for (int j = 0; j < 25; ++j) {
      const float4* pw = (const float4*)&sP[(q * 25 + j) * 12];
      float4 A = pw[0], B = pw[1], C = pw[2];
      float base;
      if (interior) {
        base = C.y;   // Bfull
      } else {
        base = C.z;   // enc_b
        #pragma unroll
        for (int t9 = 0; t9 < 9; ++t9)
          base += vm[t9] * sBc[(j * 4 + q) * 9 + t9];
      }
      float v = base;
      v += A.x * f[1][1]; v += A.y * f[1][2]; v += A.z * f[1][3];
      v += A.w * f[2][1]; v += B.x * f[2][2]; v += B.y * f[2][3];
      v += B.z * f[3][1]; v += B.w * f[3][2]; v += C.x * f[3][3];
      lg[j] = v;
      mx = fmaxf(mx, v);
    }
    float s = 0.f, acc = 0.f;
    #pragma unroll
    for (int j = 0; j < 25; ++j) {
      float e = __expf(lg[j] - mx);
      s += e;
      acc += e * f[j / 5][j % 5];
    }
    r[q] = acc / s;
  }

  float* orow0 = out + ((size_t)n * 1024 + 2 * h) * 1024 + 2 * w;
  float* orow1 = orow0 + 1024;
  *(float2*)orow0 = make_float2(r[0], r[1]);
  *(float2*)orow1 = make_float2(r[2], r[3]);
}

extern "C" void kernel_launch(void* const* d_in, const int* in_sizes, int n_in,
                              void* d_out, int out_size, void* d_ws, size_t ws_size,
                              hipStream_t stream) {
  const float* x      = (const float*)d_in[0];
  const float* conv_w = (const float*)d_in[1];
  const float* conv_b = (const float*)d_in[2];
  const float* comp_w = (const float*)d_in[3];
  const float* comp_b = (const float*)d_in[4];
  const float* enc_w  = (const float*)d_in[5];
  const float* enc_b  = (const float*)d_in[6];
  float* out = (float*)d_out;
  float* ws  = (float*)d_ws;

  prep_kernel<<<1, 1024, 0, stream>>>(comp_w, comp_b, enc_w, enc_b, ws);
  carafe_kernel<<<dim3(W / TILE, H / TILE, 8), 256, 0, stream>>>(
      x, conv_w, conv_b, ws, out);
}

// Round 2
// 177.737 us; speedup vs baseline: 3.3840x; 3.3840x over previous
//
#include <hip/hip_runtime.h>

#define H 512
#define W 512
#define XH 513
#define TW 32
#define TH 16
#define FTH (TH + 4)      // 20 feat rows incl 2-halo
#define FTW (TW + 4)      // 36 feat cols incl 2-halo
#define FSW (FTW + 1)     // 37 LDS stride

// ws layout (floats), all logit-space values pre-scaled by log2(e):
// [0, 1200)    : P[4][25][12] = {w0..w8, Bfull, enc_b, pad} per (q, j)
// [1200, 2100) : Bc[100][9]   per-tap bias (border correction), o = j*4+q

__global__ __launch_bounds__(1024)
void prep_kernel(const float* __restrict__ comp_w, const float* __restrict__ comp_b,
                 const float* __restrict__ enc_w, const float* __restrict__ enc_b,
                 float* __restrict__ ws) {
  const float L2E = 1.4426950408889634f;
  int t = threadIdx.x;
  float* P  = ws;
  float* Bc = ws + 1200;
  if (t < 900) {
    int o = t / 9, tap = t % 9;
    float sw = 0.f, sb = 0.f;
    for (int c = 0; c < 64; ++c) {
      float e = enc_w[(o * 64 + c) * 9 + tap];
      sw += e * comp_w[c];
      sb += e * comp_b[c];
    }
    int q = o & 3, j = o >> 2;
    P[(q * 25 + j) * 12 + tap] = sw * L2E;
    Bc[o * 9 + tap] = sb * L2E;
  }
  __syncthreads();
  if (t < 100) {
    int o = t;
    float s = enc_b[o] * L2E;
    for (int i = 0; i < 9; ++i) s += Bc[o * 9 + i];
    int q = o & 3, j = o >> 2;
    P[(q * 25 + j) * 12 + 9]  = s;               // Bfull (interior, log2 dom.)
    P[(q * 25 + j) * 12 + 10] = enc_b[o] * L2E;  // raw enc bias (border path)
    P[(q * 25 + j) * 12 + 11] = 0.f;
  }
}

__global__ __launch_bounds__(256)
void carafe_kernel(const float* __restrict__ x,
                   const float* __restrict__ conv_w, const float* __restrict__ conv_b,
                   const float* __restrict__ ws,
                   float* __restrict__ out) {
  __shared__ float sF[FTH][FSW];

  int tid = threadIdx.x;
  int n  = blockIdx.z;
  int h0 = blockIdx.y * TH;
  int w0 = blockIdx.x * TW;

  float w00 = conv_w[0], w01 = conv_w[1], w10 = conv_w[2], w11 = conv_w[3];
  float cb  = conv_b[0];
  const float* xn = x + (size_t)n * XH * XH;

  // feat tile with 2-halo: feat(h,w) = cb + 2x2 conv of x, zero outside grid
  for (int i = tid; i < FTH * FTW; i += 256) {
    int r = i / FTW, c = i - r * FTW;
    int h = h0 - 2 + r, w = w0 - 2 + c;
    float v = 0.f;
    if (h >= 0 && h < H && w >= 0 && w < W) {
      const float* p = xn + (size_t)h * XH + w;
      v = cb + w00 * p[0] + w01 * p[1] + w10 * p[XH] + w11 * p[XH + 1];
    }
    sF[r][c] = v;
  }
  __syncthreads();

  int ty = tid >> 4, tx = tid & 15;
  int h = h0 + ty;
  int w = w0 + 2 * tx;   // this thread owns pixels (h,w) and (h,w+1)

  float f[5][6];
  #pragma unroll
  for (int i = 0; i < 5; ++i)
    #pragma unroll
    for (int j = 0; j < 6; ++j)
      f[i][j] = sF[ty + i][2 * tx + j];

  bool bint = (h0 >= 1) && (h0 + TH <= H - 1) && (w0 >= 1) && (w0 + TW <= W - 1);

  float p0[9], p1[9];
  if (!bint) {
    float vh[3], vw0[3], vw1[3];
    #pragma unroll
    for (int d = 0; d < 3; ++d) {
      vh[d]  = (h - 1 + d >= 0 && h - 1 + d < H) ? 1.f : 0.f;
      vw0[d] = (w - 1 + d >= 0 && w - 1 + d < W) ? 1.f : 0.f;
      vw1[d] = (w + d >= 0     && w + d < W)     ? 1.f : 0.f;
    }
    #pragma unroll
    for (int r = 0; r < 3; ++r)
      #pragma unroll
      for (int c = 0; c < 3; ++c) {
        p0[r * 3 + c] = vh[r] * vw0[c];
        p1[r * 3 + c] = vh[r] * vw1[c];
      }
  }

  float res[4][2];
  #pragma unroll 1
  for (int q = 0; q < 4; ++q) {
    const float* Pq = ws + q * 300;
    float s0 = 0.f, a0 = 0.f, s1 = 0.f, a1 = 0.f;
    #pragma unroll
    for (int j = 0; j < 25; ++j) {
      const float* pw = Pq + j * 12;   // uniform address -> s_load
      float v0, v1;
      if (bint) {
        v0 = pw[9]; v1 = pw[9];
      } else {
        const float* bc = ws + 1200 + (j * 4 + q) * 9;
        v0 = pw[10]; v1 = pw[10];
        #pragma unroll
        for (int t = 0; t < 9; ++t) {
          v0 += p0[t] * bc[t];
          v1 += p1[t] * bc[t];
        }
      }
      v0 += pw[0] * f[1][1]; v1 += pw[0] * f[1][2];
      v0 += pw[1] * f[1][2]; v1 += pw[1] * f[1][3];
      v0 += pw[2] * f[1][3]; v1 += pw[2] * f[1][4];
      v0 += pw[3] * f[2][1]; v1 += pw[3] * f[2][2];
      v0 += pw[4] * f[2][2]; v1 += pw[4] * f[2][3];
      v0 += pw[5] * f[2][3]; v1 += pw[5] * f[2][4];
      v0 += pw[6] * f[3][1]; v1 += pw[6] * f[3][2];
      v0 += pw[7] * f[3][2]; v1 += pw[7] * f[3][3];
      v0 += pw[8] * f[3][3]; v1 += pw[8] * f[3][4];
      float e0 = __builtin_amdgcn_exp2f(v0);
      float e1 = __builtin_amdgcn_exp2f(v1);
      float ff0 = f[j / 5][j % 5];
      float ff1 = f[j / 5][j % 5 + 1];
      s0 += e0; a0 += e0 * ff0;
      s1 += e1; a1 += e1 * ff1;
    }
    res[q][0] = a0 * __builtin_amdgcn_rcpf(s0);
    res[q][1] = a1 * __builtin_amdgcn_rcpf(s1);
  }

  float4 o0 = make_float4(res[0][0], res[1][0], res[0][1], res[1][1]);
  float4 o1 = make_float4(res[2][0], res[3][0], res[2][1], res[3][1]);
  float* prow = out + ((size_t)n * 1024 + 2 * h) * 1024 + 2 * w;
  *(float4*)prow          = o0;
  *(float4*)(prow + 1024) = o1;
}

extern "C" void kernel_launch(void* const* d_in, const int* in_sizes, int n_in,
                              void* d_out, int out_size, void* d_ws, size_t ws_size,
                              hipStream_t stream) {
  const float* x      = (const float*)d_in[0];
  const float* conv_w = (const float*)d_in[1];
  const float* conv_b = (const float*)d_in[2];
  const float* comp_w = (const float*)d_in[3];
  const float* comp_b = (const float*)d_in[4];
  const float* enc_w  = (const float*)d_in[5];
  const float* enc_b  = (const float*)d_in[6];
  float* out = (float*)d_out;
  float* ws  = (float*)d_ws;

  prep_kernel<<<1, 1024, 0, stream>>>(comp_w, comp_b, enc_w, enc_b, ws);
  carafe_kernel<<<dim3(W / TW, H / TH, 8), 256, 0, stream>>>(
      x, conv_w, conv_b, ws, out);
}

// Round 3
// 117.902 us; speedup vs baseline: 5.1014x; 1.5075x over previous
//
#include <hip/hip_runtime.h>

typedef float v2f __attribute__((ext_vector_type(2)));

#define H 512
#define W 512
#define XH 513
#define TPX 32              // 32x32 px tile per block (256 thr x 2x2 px)
#define FTD (TPX + 4)       // 36 feat rows/cols incl 2-halo
#define FSD (FTD + 2)       // 38 LDS stride (even)

// ws layout (floats), logit-space values pre-scaled by log2(e):
// PW  [0,1200):    rec[(qp*25+j)*24]: {w_k pairs k=0..8 (18 floats), Bfull pair (2), pad (4)}
//                  pair element b corresponds to q = qp*2+b  (o = j*4+q)
// Base[1200,2100): [(pat*25+j)*4 + qp*2 + b], pat = ph*3+pw in 0..8 (0 = interior)

__global__ __launch_bounds__(1024)
void prep_kernel(const float* __restrict__ comp_w, const float* __restrict__ comp_b,
                 const float* __restrict__ enc_w, const float* __restrict__ enc_b,
                 float* __restrict__ ws) {
  const float L2E = 1.4426950408889634f;
  __shared__ float sBc[900];
  int t = threadIdx.x;
  if (t < 900) {
    int o = t / 9, tap = t % 9;
    float sw = 0.f, sb = 0.f;
    for (int c = 0; c < 64; ++c) {
      float e = enc_w[(o * 64 + c) * 9 + tap];
      sw += e * comp_w[c];
      sb += e * comp_b[c];
    }
    int j = o >> 2, qp = (o >> 1) & 1, b = o & 1;
    ws[(qp * 25 + j) * 24 + tap * 2 + b] = sw * L2E;
    sBc[o * 9 + tap] = sb;
  }
  __syncthreads();
  if (t < 900) {
    int pat = t / 100, o = t % 100;
    int ph = pat / 3, pw_ = pat % 3;
    float s = enc_b[o];
    for (int tap = 0; tap < 9; ++tap) {
      int dr = tap / 3, dc = tap % 3;
      bool bad = (ph == 1 && dr == 0) || (ph == 2 && dr == 2) ||
                 (pw_ == 1 && dc == 0) || (pw_ == 2 && dc == 2);
      if (!bad) s += sBc[o * 9 + tap];
    }
    int j = o >> 2, qp = (o >> 1) & 1, b = o & 1;
    ws[1200 + (pat * 25 + j) * 4 + qp * 2 + b] = s * L2E;
    if (pat == 0) ws[(qp * 25 + j) * 24 + 18 + b] = s * L2E;  // Bfull
  }
}

__global__ __launch_bounds__(256)
void carafe_kernel(const float* __restrict__ x,
                   const float* __restrict__ conv_w, const float* __restrict__ conv_b,
                   const float* __restrict__ ws,
                   float* __restrict__ out) {
  __shared__ float sF[FTD][FSD];

  int tid = threadIdx.x;
  int n  = blockIdx.z;
  int h0 = blockIdx.y * TPX;
  int w0 = blockIdx.x * TPX;

  float w00 = conv_w[0], w01c = conv_w[1], w10 = conv_w[2], w11 = conv_w[3];
  float cb  = conv_b[0];
  const float* xn = x + (size_t)n * XH * XH;

  for (int i = tid; i < FTD * FTD; i += 256) {
    int r = i / FTD, c = i - r * FTD;
    int hh = h0 - 2 + r, ww = w0 - 2 + c;
    float v = 0.f;
    if (hh >= 0 && hh < H && ww >= 0 && ww < W) {
      const float* p = xn + (size_t)hh * XH + ww;
      v = cb + w00 * p[0] + w01c * p[1] + w10 * p[XH] + w11 * p[XH + 1];
    }
    sF[r][c] = v;
  }
  __syncthreads();

  int ty = tid >> 4, tx = tid & 15;
  int h = h0 + 2 * ty;      // top row of this thread's 2x2 px quad
  int w = w0 + 2 * tx;

  float f[6][6];
  #pragma unroll
  for (int i = 0; i < 6; ++i)
    #pragma unroll
    for (int j2 = 0; j2 < 6; ++j2)
      f[i][j2] = sF[2 * ty + i][2 * tx + j2];

  v2f s01[4], a01[4], s23[4], a23[4];
  #pragma unroll
  for (int p = 0; p < 4; ++p) {
    s01[p] = (v2f)(0.f); a01[p] = (v2f)(0.f);
    s23[p] = (v2f)(0.f); a23[p] = (v2f)(0.f);
  }

  bool edge = (h == 0) | (h == H - 2) | (w == 0) | (w == W - 2);

  if (!edge) {
    #pragma unroll
    for (int j = 0; j < 25; ++j) {
      const v2f* W0 = (const v2f*)(ws + j * 24);          // q0,q1 pairs
      const v2f* W1 = (const v2f*)(ws + (25 + j) * 24);   // q2,q3 pairs
      int jr = j / 5, jc = j % 5;
      #pragma unroll
      for (int p = 0; p < 4; ++p) {
        int pr = p >> 1, pc = p & 1;
        v2f v0 = W0[9];   // Bfull pair
        v2f v1 = W1[9];
        #pragma unroll
        for (int k = 0; k < 9; ++k) {
          float fv = f[pr + 1 + k / 3][pc + 1 + k % 3];
          v0 += W0[k] * fv;
          v1 += W1[k] * fv;
        }
        v2f e0, e1;
        e0.x = __builtin_amdgcn_exp2f(v0.x);
        e0.y = __builtin_amdgcn_exp2f(v0.y);
        e1.x = __builtin_amdgcn_exp2f(v1.x);
        e1.y = __builtin_amdgcn_exp2f(v1.y);
        float fj = f[pr + jr][pc + jc];
        s01[p] += e0; a01[p] += e0 * fj;
        s23[p] += e1; a23[p] += e1 * fj;
      }
    }
  } else {
    int pats[4];
    #pragma unroll
    for (int p = 0; p < 4; ++p) {
      int hr = h + (p >> 1), wc = w + (p & 1);
      int ph = (hr == 0) ? 1 : ((hr == H - 1) ? 2 : 0);
      int pw_ = (wc == 0) ? 1 : ((wc == W - 1) ? 2 : 0);
      pats[p] = ph * 3 + pw_;
    }
    #pragma unroll 1
    for (int j = 0; j < 25; ++j) {
      const v2f* W0 = (const v2f*)(ws + j * 24);
      const v2f* W1 = (const v2f*)(ws + (25 + j) * 24);
      int jr = j / 5, jc = j % 5;
      #pragma unroll
      for (int p = 0; p < 4; ++p) {
        int pr = p >> 1, pc = p & 1;
        const float* bp = ws + 1200 + (pats[p] * 25 + j) * 4;
        v2f v0 = *(const v2f*)bp;
        v2f v1 = *(const v2f*)(bp + 2);
        #pragma unroll
        for (int k = 0; k < 9; ++k) {
          float fv = f[pr + 1 + k / 3][pc + 1 + k % 3];
          v0 += W0[k] * fv;
          v1 += W1[k] * fv;
        }
        v2f e0, e1;
        e0.x = __builtin_amdgcn_exp2f(v0.x);
        e0.y = __builtin_amdgcn_exp2f(v0.y);
        e1.x = __builtin_amdgcn_exp2f(v1.x);
        e1.y = __builtin_amdgcn_exp2f(v1.y);
        float fj = sF[2 * ty + pr + jr][2 * tx + pc + jc];  // LDS: avoid runtime reg-index
        s01[p] += e0; a01[p] += e0 * fj;
        s23[p] += e1; a23[p] += e1 * fj;
      }
    }
  }

  #pragma unroll
  for (int pr = 0; pr < 2; ++pr) {
    int pl = pr * 2, prr = pr * 2 + 1;
    float4 top, bot;
    top.x = a01[pl].x * __builtin_amdgcn_rcpf(s01[pl].x);
    top.y = a01[pl].y * __builtin_amdgcn_rcpf(s01[pl].y);
    top.z = a01[prr].x * __builtin_amdgcn_rcpf(s01[prr].x);
    top.w = a01[prr].y * __builtin_amdgcn_rcpf(s01[prr].y);
    bot.x = a23[pl].x * __builtin_amdgcn_rcpf(s23[pl].x);
    bot.y = a23[pl].y * __builtin_amdgcn_rcpf(s23[pl].y);
    bot.z = a23[prr].x * __builtin_amdgcn_rcpf(s23[prr].x);
    bot.w = a23[prr].y * __builtin_amdgcn_rcpf(s23[prr].y);
    float* prow = out + ((size_t)n * 1024 + 2 * (h + pr)) * 1024 + 2 * w;
    *(float4*)prow          = top;
    *(float4*)(prow + 1024) = bot;
  }
}

extern "C" void kernel_launch(void* const* d_in, const int* in_sizes, int n_in,
                              void* d_out, int out_size, void* d_ws, size_t ws_size,
                              hipStream_t stream) {
  const float* x      = (const float*)d_in[0];
  const float* conv_w = (const float*)d_in[1];
  const float* conv_b = (const float*)d_in[2];
  const float* comp_w = (const float*)d_in[3];
  const float* comp_b = (const float*)d_in[4];
  const float* enc_w  = (const float*)d_in[5];
  const float* enc_b  = (const float*)d_in[6];
  float* out = (float*)d_out;
  float* ws  = (float*)d_ws;

  prep_kernel<<<1, 1024, 0, stream>>>(comp_w, comp_b, enc_w, enc_b, ws);
  carafe_kernel<<<dim3(W / TPX, H / TPX, 8), 256, 0, stream>>>(
      x, conv_w, conv_b, ws, out);
}

// Round 4
// 79.303 us; speedup vs baseline: 7.5844x; 1.4867x over previous
//
#include <hip/hip_runtime.h>

typedef float v2f __attribute__((ext_vector_type(2)));

#define H 512
#define W 512
#define XH 513
#define TPX 32              // 32x32 px tile, 256 thr = 2 qp x 128 slots x (4x2 px)
#define FTD (TPX + 4)       // 36 feat rows/cols incl 2-halo
#define FSD 40              // LDS row stride (160B, keeps b128 alignment)

// ws layout (floats), logit-space values pre-scaled by log2(e):
// [0,1000):    sW [qp][j][20]: {(w_k for q=2qp, q=2qp+1) k=0..8 -> 18 floats, 2 pad}
// [1000,1900): Base[pat][j][4]: per-pattern logit base, pat = ph*3+pw (0 = interior)

__global__ __launch_bounds__(1024)
void prep_kernel(const float* __restrict__ comp_w, const float* __restrict__ comp_b,
                 const float* __restrict__ enc_w, const float* __restrict__ enc_b,
                 float* __restrict__ ws) {
  const float L2E = 1.4426950408889634f;
  __shared__ float sBc[900];
  int t = threadIdx.x;
  if (t < 900) {
    int o = t / 9, tap = t % 9;
    float sw = 0.f, sb = 0.f;
    for (int c = 0; c < 64; ++c) {
      float e = enc_w[(o * 64 + c) * 9 + tap];
      sw += e * comp_w[c];
      sb += e * comp_b[c];
    }
    int j = o >> 2, qp = (o >> 1) & 1, b = o & 1;
    ws[(qp * 25 + j) * 20 + tap * 2 + b] = sw * L2E;
    sBc[o * 9 + tap] = sb;
  }
  __syncthreads();
  if (t < 900) {
    int pat = t / 100, o = t % 100;
    int ph = pat / 3, pw_ = pat % 3;
    float s = enc_b[o];
    for (int tap = 0; tap < 9; ++tap) {
      int dr = tap / 3, dc = tap % 3;
      bool bad = (ph == 1 && dr == 0) || (ph == 2 && dr == 2) ||
                 (pw_ == 1 && dc == 0) || (pw_ == 2 && dc == 2);
      if (!bad) s += sBc[o * 9 + tap];
    }
    int j = o >> 2, q = o & 3;
    ws[1000 + (pat * 25 + j) * 4 + q] = s * L2E;
  }
  if (t < 100) {  // zero sW pad slots
    int qp = (t >> 1) & 1, j = t >> 2, b = t & 1;
    ws[(qp * 25 + j) * 20 + 18 + b] = 0.f;
  }
}

__global__ __launch_bounds__(256)
void carafe_kernel(const float* __restrict__ x,
                   const float* __restrict__ conv_w, const float* __restrict__ conv_b,
                   const float* __restrict__ ws,
                   float* __restrict__ out) {
  __shared__ __align__(16) float sW[1000];
  __shared__ __align__(16) float sBase[900];
  __shared__ __align__(16) float sF[FTD][FSD];

  int tid = threadIdx.x;
  int n  = blockIdx.z;
  int h0 = blockIdx.y * TPX;
  int w0 = blockIdx.x * TPX;

  for (int i = tid; i < 1000; i += 256) sW[i] = ws[i];
  for (int i = tid; i < 900;  i += 256) sBase[i] = ws[1000 + i];

  float w00 = conv_w[0], w01c = conv_w[1], w10 = conv_w[2], w11 = conv_w[3];
  float cb  = conv_b[0];
  const float* xn = x + (size_t)n * XH * XH;

  for (int i = tid; i < FTD * FTD; i += 256) {
    int r = i / FTD, c = i - r * FTD;
    int hh = h0 - 2 + r, ww = w0 - 2 + c;
    float v = 0.f;
    if (hh >= 0 && hh < H && ww >= 0 && ww < W) {
      const float* p = xn + (size_t)hh * XH + ww;
      v = cb + w00 * p[0] + w01c * p[1] + w10 * p[XH] + w11 * p[XH + 1];
    }
    sF[r][c] = v;
  }
  __syncthreads();

  int qp   = tid >> 7;        // wave-uniform: waves 0,1 -> qp0; 2,3 -> qp1
  int slot = tid & 127;
  int sx = slot & 7, sy = slot >> 3;
  int y0 = h0 + 2 * sy;       // thread's px block: rows y0..y0+1, cols x0..x0+3
  int x0 = w0 + 4 * sx;

  // patch registers: f[i][c] = feat(y0 + i - 2, x0 + c - 2)
  float f[6][8];
  #pragma unroll
  for (int i = 0; i < 6; ++i)
    #pragma unroll
    for (int c = 0; c < 8; ++c)
      f[i][c] = sF[2 * sy + i][4 * sx + c];

  // per-px base pointers into sBase (interior px -> pat 0 -> broadcast reads)
  const v2f* bp[8];
  #pragma unroll
  for (int p = 0; p < 8; ++p) {
    int yy = y0 + (p >> 2), xx = x0 + (p & 3);
    int ph = (yy == 0) ? 1 : ((yy == H - 1) ? 2 : 0);
    int pw_ = (xx == 0) ? 1 : ((xx == W - 1) ? 2 : 0);
    bp[p] = (const v2f*)(sBase + (ph * 3 + pw_) * 100 + 2 * qp);
  }

  v2f s[8], a[8];
  #pragma unroll
  for (int p = 0; p < 8; ++p) { s[p] = (v2f)(0.f); a[p] = (v2f)(0.f); }

  const float* wq = sW + qp * 500;

  #pragma unroll
  for (int j = 0; j < 25; ++j) {
    v2f Wv[9];
    #pragma unroll
    for (int k = 0; k < 9; ++k)
      Wv[k] = *(const v2f*)(wq + j * 20 + 2 * k);   // merges to b128s, uniform addr
    int jr = j / 5, jc = j % 5;
    #pragma unroll
    for (int p = 0; p < 8; ++p) {
      int pr = p >> 2, pc = p & 3;
      v2f v = bp[p][j * 2];                          // ds_read_b64 offset:j*16
      #pragma unroll
      for (int k = 0; k < 9; ++k)
        v += Wv[k] * f[pr + 1 + k / 3][pc + 1 + k % 3];
      v2f e;
      e.x = __builtin_amdgcn_exp2f(v.x);
      e.y = __builtin_amdgcn_exp2f(v.y);
      float fj = f[pr + jr][pc + jc];
      s[p] += e;
      a[p] += e * fj;
    }
  }

  #pragma unroll
  for (int pr = 0; pr < 2; ++pr) {
    v2f r[4];
    #pragma unroll
    for (int pc = 0; pc < 4; ++pc) {
      int p = pr * 4 + pc;
      r[pc].x = a[p].x * __builtin_amdgcn_rcpf(s[p].x);
      r[pc].y = a[p].y * __builtin_amdgcn_rcpf(s[p].y);
    }
    float* prow = out + ((size_t)n * 1024 + 2 * (y0 + pr) + qp) * 1024 + 2 * x0;
    *(float4*)prow       = make_float4(r[0].x, r[0].y, r[1].x, r[1].y);
    *(float4*)(prow + 4) = make_float4(r[2].x, r[2].y, r[3].x, r[3].y);
  }
}

extern "C" void kernel_launch(void* const* d_in, const int* in_sizes, int n_in,
                              void* d_out, int out_size, void* d_ws, size_t ws_size,
                              hipStream_t stream) {
  const float* x      = (const float*)d_in[0];
  const float* conv_w = (const float*)d_in[1];
  const float* conv_b = (const float*)d_in[2];
  const float* comp_w = (const float*)d_in[3];
  const float* comp_b = (const float*)d_in[4];
  const float* enc_w  = (const float*)d_in[5];
  const float* enc_b  = (const float*)d_in[6];
  float* out = (float*)d_out;
  float* ws  = (float*)d_ws;

  prep_kernel<<<1, 1024, 0, stream>>>(comp_w, comp_b, enc_w, enc_b, ws);
  carafe_kernel<<<dim3(W / TPX, H / TPX, 8), 256, 0, stream>>>(
      x, conv_w, conv_b, ws, out);
}

// Round 5
// 79.102 us; speedup vs baseline: 7.6036x; 1.0025x over previous
//
#include <hip/hip_runtime.h>

typedef float v2f __attribute__((ext_vector_type(2)));

#define H 512
#define W 512
#define XH 513
#define TPX 32              // 32x32 px tile, 256 thr = 2 qp x 128 slots x (2x4 px)
#define FTD (TPX + 4)       // 36 feat rows/cols incl 2-halo
#define FSD 40              // LDS row stride (160B, keeps b128 alignment)

// ws layout (floats), logit-space values pre-scaled by log2(e):
// [0,1000):    sW [qp][j][20]: {interior base pair (2), (w_k for q=2qp,2qp+1) k=0..8 (18)}
//              -> exactly 5 x ds_read_b128 per (qp, j), incl. base
// [1000,1900): Base[pat][j][4]: per-pattern logit base, pat = ph*3+pw (0 = interior)

__global__ __launch_bounds__(1024)
void prep_kernel(const float* __restrict__ comp_w, const float* __restrict__ comp_b,
                 const float* __restrict__ enc_w, const float* __restrict__ enc_b,
                 float* __restrict__ ws) {
  const float L2E = 1.4426950408889634f;
  __shared__ float sBc[900];
  int t = threadIdx.x;
  if (t < 900) {
    int o = t / 9, tap = t % 9;
    float sw = 0.f, sb = 0.f;
    for (int c = 0; c < 64; ++c) {
      float e = enc_w[(o * 64 + c) * 9 + tap];
      sw += e * comp_w[c];
      sb += e * comp_b[c];
    }
    int j = o >> 2, qp = (o >> 1) & 1, b = o & 1;
    ws[(qp * 25 + j) * 20 + 2 + tap * 2 + b] = sw * L2E;
    sBc[o * 9 + tap] = sb;
  }
  __syncthreads();
  if (t < 900) {
    int pat = t / 100, o = t % 100;
    int ph = pat / 3, pw_ = pat % 3;
    float s = enc_b[o];
    for (int tap = 0; tap < 9; ++tap) {
      int dr = tap / 3, dc = tap % 3;
      bool bad = (ph == 1 && dr == 0) || (ph == 2 && dr == 2) ||
                 (pw_ == 1 && dc == 0) || (pw_ == 2 && dc == 2);
      if (!bad) s += sBc[o * 9 + tap];
    }
    int j = o >> 2, q = o & 3;
    ws[1000 + (pat * 25 + j) * 4 + q] = s * L2E;
    if (pat == 0) ws[((q >> 1) * 25 + j) * 20 + (q & 1)] = s * L2E;  // interior base
  }
}

__global__ __launch_bounds__(256)
void carafe_kernel(const float* __restrict__ x,
                   const float* __restrict__ conv_w, const float* __restrict__ conv_b,
                   const float* __restrict__ ws,
                   float* __restrict__ out) {
  __shared__ __align__(16) float sW[1000];
  __shared__ __align__(16) float sBase[900];
  __shared__ __align__(16) float sF[FTD][FSD];

  int tid = threadIdx.x;
  int n  = blockIdx.z;
  int h0 = blockIdx.y * TPX;
  int w0 = blockIdx.x * TPX;

  for (int i = tid; i < 1000; i += 256) sW[i] = ws[i];
  for (int i = tid; i < 900;  i += 256) sBase[i] = ws[1000 + i];

  float w00 = conv_w[0], w01c = conv_w[1], w10 = conv_w[2], w11 = conv_w[3];
  float cb  = conv_b[0];
  const float* xn = x + (size_t)n * XH * XH;

  for (int i = tid; i < FTD * FTD; i += 256) {
    int r = i / FTD, c = i - r * FTD;
    int hh = h0 - 2 + r, ww = w0 - 2 + c;
    float v = 0.f;
    if (hh >= 0 && hh < H && ww >= 0 && ww < W) {
      const float* p = xn + (size_t)hh * XH + ww;
      v = cb + w00 * p[0] + w01c * p[1] + w10 * p[XH] + w11 * p[XH + 1];
    }
    sF[r][c] = v;
  }
  __syncthreads();

  int qp   = tid >> 7;        // wave-uniform: waves 0,1 -> qp0; 2,3 -> qp1
  int slot = tid & 127;
  int sx = slot & 7, sy = slot >> 3;
  int y0 = h0 + 2 * sy;       // thread's px block: rows y0..y0+1, cols x0..x0+3
  int x0 = w0 + 4 * sx;

  // patch registers: f[i][c] = feat(y0 + i - 2, x0 + c - 2), via b128 reads
  float f[6][8];
  #pragma unroll
  for (int i = 0; i < 6; ++i) {
    float4 lo = *(const float4*)&sF[2 * sy + i][4 * sx];
    float4 hi = *(const float4*)&sF[2 * sy + i][4 * sx + 4];
    f[i][0] = lo.x; f[i][1] = lo.y; f[i][2] = lo.z; f[i][3] = lo.w;
    f[i][4] = hi.x; f[i][5] = hi.y; f[i][6] = hi.z; f[i][7] = hi.w;
  }

  v2f s[8], a[8];
  #pragma unroll
  for (int p = 0; p < 8; ++p) { s[p] = (v2f)(0.f); a[p] = (v2f)(0.f); }

  const float* wq = sW + qp * 500;
  bool border = (blockIdx.x == 0) | (blockIdx.x == (W / TPX - 1)) |
                (blockIdx.y == 0) | (blockIdx.y == (H / TPX - 1));

  if (!border) {
    #pragma unroll
    for (int j = 0; j < 25; ++j) {
      float4 r0 = *(const float4*)(wq + j * 20);
      float4 r1 = *(const float4*)(wq + j * 20 + 4);
      float4 r2 = *(const float4*)(wq + j * 20 + 8);
      float4 r3 = *(const float4*)(wq + j * 20 + 12);
      float4 r4 = *(const float4*)(wq + j * 20 + 16);
      v2f base; base.x = r0.x; base.y = r0.y;
      v2f Wk[9];
      Wk[0].x = r0.z; Wk[0].y = r0.w;
      Wk[1].x = r1.x; Wk[1].y = r1.y;
      Wk[2].x = r1.z; Wk[2].y = r1.w;
      Wk[3].x = r2.x; Wk[3].y = r2.y;
      Wk[4].x = r2.z; Wk[4].y = r2.w;
      Wk[5].x = r3.x; Wk[5].y = r3.y;
      Wk[6].x = r3.z; Wk[6].y = r3.w;
      Wk[7].x = r4.x; Wk[7].y = r4.y;
      Wk[8].x = r4.z; Wk[8].y = r4.w;
      int jr = j / 5, jc = j % 5;
      #pragma unroll
      for (int p = 0; p < 8; ++p) {
        int pr = p >> 2, pc = p & 3;
        v2f v = base;
        #pragma unroll
        for (int k = 0; k < 9; ++k)
          v += Wk[k] * f[pr + 1 + k / 3][pc + 1 + k % 3];
        v2f e;
        e.x = __builtin_amdgcn_exp2f(v.x);
        e.y = __builtin_amdgcn_exp2f(v.y);
        float fj = f[pr + jr][pc + jc];
        s[p] += e;
        a[p] += e * fj;
      }
    }
  } else {
    const v2f* bp[8];
    #pragma unroll
    for (int p = 0; p < 8; ++p) {
      int yy = y0 + (p >> 2), xx = x0 + (p & 3);
      int ph = (yy == 0) ? 1 : ((yy == H - 1) ? 2 : 0);
      int pw_ = (xx == 0) ? 1 : ((xx == W - 1) ? 2 : 0);
      bp[p] = (const v2f*)(sBase + (ph * 3 + pw_) * 100 + 2 * qp);
    }
    #pragma unroll
    for (int j = 0; j < 25; ++j) {
      float4 r0 = *(const float4*)(wq + j * 20);
      float4 r1 = *(const float4*)(wq + j * 20 + 4);
      float4 r2 = *(const float4*)(wq + j * 20 + 8);
      float4 r3 = *(const float4*)(wq + j * 20 + 12);
      float4 r4 = *(const float4*)(wq + j * 20 + 16);
      v2f Wk[9];
      Wk[0].x = r0.z; Wk[0].y = r0.w;
      Wk[1].x = r1.x; Wk[1].y = r1.y;
      Wk[2].x = r1.z; Wk[2].y = r1.w;
      Wk[3].x = r2.x; Wk[3].y = r2.y;
      Wk[4].x = r2.z; Wk[4].y = r2.w;
      Wk[5].x = r3.x; Wk[5].y = r3.y;
      Wk[6].x = r3.z; Wk[6].y = r3.w;
      Wk[7].x = r4.x; Wk[7].y = r4.y;
      Wk[8].x = r4.z; Wk[8].y = r4.w;
      int jr = j / 5, jc = j % 5;
      #pragma unroll
      for (int p = 0; p < 8; ++p) {
        int pr = p >> 2, pc = p & 3;
        v2f v = bp[p][j * 2];                 // ds_read_b64 offset:j*16
        #pragma unroll
        for (int k = 0; k < 9; ++k)
          v += Wk[k] * f[pr + 1 + k / 3][pc + 1 + k % 3];
        v2f e;
        e.x = __builtin_amdgcn_exp2f(v.x);
        e.y = __builtin_amdgcn_exp2f(v.y);
        float fj = f[pr + jr][pc + jc];
        s[p] += e;
        a[p] += e * fj;
      }
    }
  }

  #pragma unroll
  for (int pr = 0; pr < 2; ++pr) {
    v2f r[4];
    #pragma unroll
    for (int pc = 0; pc < 4; ++pc) {
      int p = pr * 4 + pc;
      r[pc].x = a[p].x * __builtin_amdgcn_rcpf(s[p].x);
      r[pc].y = a[p].y * __builtin_amdgcn_rcpf(s[p].y);
    }
    float* prow = out + ((size_t)n * 1024 + 2 * (y0 + pr) + qp) * 1024 + 2 * x0;
    *(float4*)prow       = make_float4(r[0].x, r[0].y, r[1].x, r[1].y);
    *(float4*)(prow + 4) = make_float4(r[2].x, r[2].y, r[3].x, r[3].y);
  }
}

extern "C" void kernel_launch(void* const* d_in, const int* in_sizes, int n_in,
                              void* d_out, int out_size, void* d_ws, size_t ws_size,
                              hipStream_t stream) {
  const float* x      = (const float*)d_in[0];
  const float* conv_w = (const float*)d_in[1];
  const float* conv_b = (const float*)d_in[2];
  const float* comp_w = (const float*)d_in[3];
  const float* comp_b = (const float*)d_in[4];
  const float* enc_w  = (const float*)d_in[5];
  const float* enc_b  = (const float*)d_in[6];
  float* out = (float*)d_out;
  float* ws  = (float*)d_ws;

  prep_kernel<<<1, 1024, 0, stream>>>(comp_w, comp_b, enc_w, enc_b, ws);
  carafe_kernel<<<dim3(W / TPX, H / TPX, 8), 256, 0, stream>>>(
      x, conv_w, conv_b, ws, out);
}